// Round 13
// baseline (98.627 us; speedup 1.0000x reference)
//
#include <hip/hip_runtime.h>

typedef unsigned short u16;
typedef unsigned int u32;
using f32x4 = __attribute__((ext_vector_type(4))) float;
using s16x8 = __attribute__((ext_vector_type(8))) short;
using u16x4 = __attribute__((ext_vector_type(4))) unsigned short;
using u16x8 = __attribute__((ext_vector_type(8))) unsigned short;

#define GLOAD_LDS16(g, s)                                     \
  __builtin_amdgcn_global_load_lds(                           \
      (const __attribute__((address_space(1))) void*)(g),     \
      (__attribute__((address_space(3))) void*)(s), 16, 0, 0)

namespace {

constexpr int T = 1024;
constexpr int C = 512;
constexpr float QSCALE = 0.125f * 1.4426950408889634f;  // 1/8 * log2(e)
constexpr float MASKED = -14427.0f;                     // -10000 * log2(e)
constexpr float DEFER_THR = 11.0f;

__device__ inline u16 f2bf(float f) {
  u32 u = __builtin_bit_cast(u32, f);
  u32 r = (u + 0x7fffu + ((u >> 16) & 1u)) >> 16;
  return (u16)r;
}
__device__ inline float bf2f(u16 v) {
  return __builtin_bit_cast(float, (u32)v << 16);
}
__device__ inline f32x4 mfma16(s16x8 a, s16x8 b, f32x4 c) {
  return __builtin_amdgcn_mfma_f32_16x16x32_bf16(a, b, c, 0, 0, 0);
}
__device__ inline u32 cvtpk(float lo, float hi) {
  u32 r;
  asm("v_cvt_pk_bf16_f32 %0, %1, %2" : "=v"(r) : "v"(lo), "v"(hi));
  return r;
}

// ---------------------------------------------------------------------------
// fp32 -> bf16 conversion (separate kernel: streaming, prefetch-friendly)
// ---------------------------------------------------------------------------
__global__ __launch_bounds__(256) void convert_all(
    const float* __restrict__ x, const float* __restrict__ Wq,
    const float* __restrict__ Wk, const float* __restrict__ Wv,
    const float* __restrict__ Wo, u16* __restrict__ xb, u16* __restrict__ Wqb,
    u16* __restrict__ Wkb, u16* __restrict__ Wvb, u16* __restrict__ Wob) {
  const int tid = threadIdx.x;
  const int bid = blockIdx.x;
  const float* src;
  u16* dst;
  size_t off;
  if (bid < 2048) {
    src = x; dst = xb;
    off = ((size_t)bid * 256 + tid) * 4;
  } else {
    const int j = bid - 2048;
    const int w = j >> 8;
    src = w == 0 ? Wq : w == 1 ? Wk : w == 2 ? Wv : Wo;
    dst = w == 0 ? Wqb : w == 1 ? Wkb : w == 2 ? Wvb : Wob;
    off = (((size_t)(j & 255)) * 256 + tid) * 4;
  }
  const float4 v = *reinterpret_cast<const float4*>(src + off);
  u16x4 o;
  o[0] = f2bf(v.x); o[1] = f2bf(v.y); o[2] = f2bf(v.z); o[3] = f2bf(v.w);
  *reinterpret_cast<u16x4*>(dst + off) = o;
}

// ---------------------------------------------------------------------------
// Fused q/k/v projection GEMM (bf16 MFMA).  Y[o][t] = sum_c W[o][c] x[c][t].
// q: [b][h][t][dd] bf16, PRE-SCALED by QSCALE (log2-domain scores).
// k,v: PRE-SWIZZLED tile images for linear DMA into LDS.
// ---------------------------------------------------------------------------
__global__ __launch_bounds__(256) void qkv_gemm(
    const u16* __restrict__ xb, const u16* __restrict__ Wqb,
    const u16* __restrict__ Wkb, const u16* __restrict__ Wvb,
    const float* __restrict__ bq, const float* __restrict__ bk,
    const float* __restrict__ bv, u16* __restrict__ qb, u16* __restrict__ kswz,
    u16* __restrict__ vswz) {
  __shared__ u16 Bs[2][128 * 32];
  __shared__ float sbias[64];
  const int tid = threadIdx.x;
  const int z = blockIdx.z;
  const int b = z / 3, wsel = z - 3 * b;
  const u16* W = wsel == 0 ? Wqb : wsel == 1 ? Wkb : Wvb;
  const float* bias = wsel == 0 ? bq : wsel == 1 ? bk : bv;
  const int o0 = blockIdx.y * 64;
  const int t0 = blockIdx.x * 128;
  if (tid < 16)
    *reinterpret_cast<float4*>(&sbias[tid * 4]) =
        *reinterpret_cast<const float4*>(&bias[o0 + tid * 4]);

  const int l = tid & 63, wid = tid >> 6;
  const int wm = wid >> 1, wn = wid & 1;
  const int lr = l & 15, lg = l >> 4;

  const int cpair = tid & 15, tgrp = tid >> 4;
  const u16* xrow =
      xb + ((size_t)(b * C) + 2 * cpair) * T + t0 + 8 * tgrp;

  const u16* Arow0 = W + (size_t)(o0 + 32 * wm + lr) * C + 8 * lg;
  const u16* Arow1 = Arow0 + 16 * C;

  f32x4 acc[2][4] = {};

  auto stage = [&](int kk, int buf) {
    const u16* p = xrow + (size_t)kk * 32 * T;
    const u16x8 v0 = *reinterpret_cast<const u16x8*>(p);
    const u16x8 v1 = *reinterpret_cast<const u16x8*>(p + T);
    char* base = (char*)&Bs[buf][0];
#pragma unroll
    for (int j = 0; j < 8; ++j) {
      const int t = 8 * tgrp + j;
      const u32 w2 = (u32)v0[j] | ((u32)v1[j] << 16);
      *(u32*)(base + ((t * 64 + 4 * cpair) ^ ((t & 3) << 4))) = w2;
    }
  };

  s16x8 a0 = *reinterpret_cast<const s16x8*>(Arow0);
  s16x8 a1 = *reinterpret_cast<const s16x8*>(Arow1);
  stage(0, 0);
  __syncthreads();

  for (int kk = 0; kk < 16; ++kk) {
    s16x8 an0, an1;
    if (kk < 15) {
      an0 = *reinterpret_cast<const s16x8*>(Arow0 + (kk + 1) * 32);
      an1 = *reinterpret_cast<const s16x8*>(Arow1 + (kk + 1) * 32);
      stage(kk + 1, (kk + 1) & 1);
    }
    const char* rb = (const char*)&Bs[kk & 1][0];
#pragma unroll
    for (int nf = 0; nf < 4; ++nf) {
      const int t = 64 * wn + 16 * nf + lr;
      const s16x8 bfrag = *reinterpret_cast<const s16x8*>(
          rb + ((t * 64 + 16 * lg) ^ ((t & 3) << 4)));
      acc[0][nf] = mfma16(a0, bfrag, acc[0][nf]);
      acc[1][nf] = mfma16(a1, bfrag, acc[1][nf]);
    }
    __syncthreads();
    if (kk < 15) { a0 = an0; a1 = an1; }
  }

  const int h = o0 >> 6;
  const size_t bh = (size_t)(b * 8 + h);
  if (wsel == 0) {
#pragma unroll
    for (int m = 0; m < 2; ++m) {
      const int ob = 32 * wm + 16 * m + 4 * lg;
#pragma unroll
      for (int nf = 0; nf < 4; ++nf) {
        const int t = t0 + 64 * wn + 16 * nf + lr;
        u16x4 pk;
#pragma unroll
        for (int r = 0; r < 4; ++r)
          pk[r] = f2bf((acc[m][nf][r] + sbias[ob + r]) * QSCALE);
        *reinterpret_cast<u16x4*>(&qb[(bh * T + t) * 64 + ob]) = pk;
      }
    }
  } else if (wsel == 1) {  // K -> swizzled tile image
    char* kbase = (char*)kswz;
#pragma unroll
    for (int m = 0; m < 2; ++m) {
      const int ob = 32 * wm + 16 * m + 4 * lg;
#pragma unroll
      for (int nf = 0; nf < 4; ++nf) {
        const int t = t0 + 64 * wn + 16 * nf + lr;
        const int tile = t >> 6, row = t & 63;
        u16x4 pk;
#pragma unroll
        for (int r = 0; r < 4; ++r) pk[r] = f2bf(acc[m][nf][r] + sbias[ob + r]);
        const int off = (row * 128 + 2 * ob) ^ ((row & 7) << 4);
        *(u16x4*)(kbase + (bh * 16 + tile) * 8192 + off) = pk;
      }
    }
  } else {  // V -> swizzled tile image, scalar stores
    char* vbase = (char*)vswz;
#pragma unroll
    for (int m = 0; m < 2; ++m) {
      const int ob = 32 * wm + 16 * m + 4 * lg;
#pragma unroll
      for (int nf = 0; nf < 4; ++nf) {
        const int t = t0 + 64 * wn + 16 * nf + lr;
        const int tile = t >> 6, col2 = 2 * (t & 63);
#pragma unroll
        for (int r = 0; r < 4; ++r) {
          const int dd = ob + r;
          const int off = (dd * 128 + col2) ^ ((dd & 7) << 4);
          *(u16*)(vbase + (bh * 16 + tile) * 8192 + off) =
              f2bf(acc[m][nf][r] + sbias[dd]);
        }
      }
    }
  }
}

// ---------------------------------------------------------------------------
// MFMA flash attention (R10-proven): swapped QK^T, in-register softmax,
// 8-wave blocks, split-2, PAIR PROCESSING (128 s-cols / iteration).
// Shuffle redistribute for the PV A-fragment; one barrier per pair.
// ---------------------------------------------------------------------------
__global__ __launch_bounds__(512) void attn_swapped(
    const u16* __restrict__ qb, const u16* __restrict__ kswz,
    const u16* __restrict__ vswz, const int* __restrict__ gmask,
    const float* __restrict__ ek, const float* __restrict__ ev,
    u16* __restrict__ op0, u16* __restrict__ op1, float2* __restrict__ mlb) {
  __shared__ u16 Kbuf[2][8192];   // pair image: 2 tiles x 4096 u16 (16 KB)
  __shared__ u16 Vbuf[2][8192];
  __shared__ u16 Pdiag[8][256];
  __shared__ float rkk[128][12];
  __shared__ float eks[9][64];
  __shared__ float evs[9][64];
  __shared__ u16 zerobuf[16];
  __shared__ int tflag[16];

  const int z = blockIdx.z;
  const int b = z >> 1, shalf = z & 1;
  const int h = blockIdx.y, tc = blockIdx.x * 128;
  const int tid = threadIdx.x;
  const int l = tid & 63, wid = tid >> 6;  // 8 waves
  const int lr = l & 15, lg = l >> 4;

  const size_t bh = (size_t)(b * 8 + h);
  const u16* qbh = qb + bh * T * 64;
  const u16* kimg0 = kswz + bh * 65536;
  const u16* vimg0 = vswz + bh * 65536;

  if (tid < 144) {
    reinterpret_cast<float4*>(&eks[0][0])[tid] =
        reinterpret_cast<const float4*>(ek)[tid];
    reinterpret_cast<float4*>(&evs[0][0])[tid] =
        reinterpret_cast<const float4*>(ev)[tid];
  }
  if (tid < 16) { tflag[tid] = 1; zerobuf[tid] = 0; }
  __syncthreads();  // eks/evs visible

  // async stage of a PAIR of K/V tiles (16 KB each of K and V)
  auto stage_pair = [&](int stp, int buf) {
    const u16* ki = kimg0 + (size_t)stp * 4096;
    const u16* vi = vimg0 + (size_t)stp * 4096;
#pragma unroll
    for (int j = 0; j < 2; ++j) {
      const int seg = wid + 8 * j;  // 16 segments x 512 u16
      GLOAD_LDS16(ki + seg * 512 + l * 8, &Kbuf[buf][seg * 512]);
      GLOAD_LDS16(vi + seg * 512 + l * 8, &Vbuf[buf][seg * 512]);
    }
  };
  const int st0 = shalf * 8;
  stage_pair(st0, 0);  // flies under the prologue below

  // per-tile mask flags (all-ones fast path)
  if (tid < 256) {
    const int4 mm = reinterpret_cast<const int4*>(gmask + b * T)[tid];
    if (!(mm.x && mm.y && mm.z && mm.w)) tflag[tid >> 4] = 0;  // benign race
  }

  {  // rkk[r][w] = Qscaled[tc+r].ek[w]: 4 threads per row, 2-shuffle reduce
    const int r = tid >> 2, sub = tid & 3;
    const u16* qp = qbh + (size_t)(tc + r) * 64 + sub * 16;
    const u16x8 q0 = *reinterpret_cast<const u16x8*>(qp);
    const u16x8 q1 = *reinterpret_cast<const u16x8*>(qp + 8);
    float qf[16];
#pragma unroll
    for (int j = 0; j < 8; ++j) {
      qf[j] = bf2f(q0[j]);
      qf[j + 8] = bf2f(q1[j]);
    }
    float part[9];
#pragma unroll
    for (int w = 0; w < 9; ++w) {
      float s = 0.f;
      const float* er = &eks[w][sub * 16];
#pragma unroll
      for (int d = 0; d < 16; ++d) s += qf[d] * er[d];
      part[w] = s;
    }
#pragma unroll
    for (int w = 0; w < 9; ++w) {
      part[w] += __shfl_xor(part[w], 1);
      part[w] += __shfl_xor(part[w], 2);
    }
    if (sub == 0) {
#pragma unroll
      for (int w = 0; w < 9; ++w) rkk[r][w] = part[w];
    }
  }

  // Q B-frags direct from global (L2-hot)
  const int tbw = tc + 16 * wid;
  const int qg = tbw + lr;
  s16x8 aq0, aq1;
  {
    const u16* qgp = qbh + (size_t)qg * 64;
    aq0 = *reinterpret_cast<const s16x8*>(qgp + 8 * lg);
    aq1 = *reinterpret_cast<const s16x8*>(qgp + 32 + 8 * lg);
  }

  // ev^T A-fragments (rows dd, k = w zero-padded)
  s16x8 evA[4];
#pragma unroll
  for (int nf = 0; nf < 4; ++nf) {
    const int dd = 16 * nf + lr;
#pragma unroll
    for (int e = 0; e < 8; ++e) {
      float v = 0.f;
      if (lg == 0) v = evs[e][dd];
      else if (lg == 1 && e == 0) v = evs[8][dd];
      evA[nf][e] = (short)f2bf(v);
    }
  }

  float m = -1e30f, lsum = 0.f;
  f32x4 Oa[4] = {};
  u16* Pd = &Pdiag[wid][0];

  __syncthreads();  // rkk + tflag visible; pair-0 DMA drained

  // pack fp32 P-quad + redistribute into the PV B-fragment lane layout
  auto redist = [&](const f32x4* St, s16x8& pv0, s16x8& pv1) {
    u32 wpk[4][2];
#pragma unroll
    for (int nf = 0; nf < 4; ++nf) {
      wpk[nf][0] = cvtpk(St[nf][0], St[nf][1]);
      wpk[nf][1] = cvtpk(St[nf][2], St[nf][3]);
    }
    const int srcLo = lr + ((lg & 1) << 5);
    const int srcHi = srcLo + 16;
    const bool hiSel = (lg >> 1) != 0;
    union { u32 u[4]; s16x8 v; } pa0, pa1;
    {
      const u32 a0_ = __shfl((int)wpk[0][0], srcLo), b0_ = __shfl((int)wpk[1][0], srcLo);
      const u32 a1_ = __shfl((int)wpk[0][1], srcLo), b1_ = __shfl((int)wpk[1][1], srcLo);
      const u32 a2_ = __shfl((int)wpk[0][0], srcHi), b2_ = __shfl((int)wpk[1][0], srcHi);
      const u32 a3_ = __shfl((int)wpk[0][1], srcHi), b3_ = __shfl((int)wpk[1][1], srcHi);
      pa0.u[0] = hiSel ? b0_ : a0_; pa0.u[1] = hiSel ? b1_ : a1_;
      pa0.u[2] = hiSel ? b2_ : a2_; pa0.u[3] = hiSel ? b3_ : a3_;
    }
    {
      const u32 a0_ = __shfl((int)wpk[2][0], srcLo), b0_ = __shfl((int)wpk[3][0], srcLo);
      const u32 a1_ = __shfl((int)wpk[2][1], srcLo), b1_ = __shfl((int)wpk[3][1], srcLo);
      const u32 a2_ = __shfl((int)wpk[2][0], srcHi), b2_ = __shfl((int)wpk[3][0], srcHi);
      const u32 a3_ = __shfl((int)wpk[2][1], srcHi), b3_ = __shfl((int)wpk[3][1], srcHi);
      pa1.u[0] = hiSel ? b0_ : a0_; pa1.u[1] = hiSel ? b1_ : a1_;
      pa1.u[2] = hiSel ? b2_ : a2_; pa1.u[3] = hiSel ? b3_ : a3_;
    }
    pv0 = pa0.v;
    pv1 = pa1.v;
  };

  int cur = 0;
  for (int ii = 0; ii < 4; ++ii) {
    const int stp = st0 + 2 * ii;
    const int s0 = stp * 64, s1 = s0 + 64;
    if (ii < 3) stage_pair(stp + 2, cur ^ 1);

    // S^T = K Q^T for BOTH tiles (two independent chains)
    f32x4 StA[4] = {}, StB[4] = {};
    const char* ksb = (const char*)&Kbuf[cur][0];
#pragma unroll
    for (int nf = 0; nf < 4; ++nf) {
      const int srow = 16 * nf + lr;
      const int swz = (srow & 7) << 4;
      const int o0_ = (srow * 128 + 16 * lg) ^ swz;
      const int o1_ = (srow * 128 + 16 * (lg + 4)) ^ swz;
      const s16x8 ka0 = *reinterpret_cast<const s16x8*>(ksb + o0_);
      const s16x8 ka1 = *reinterpret_cast<const s16x8*>(ksb + o1_);
      const s16x8 kb0 = *reinterpret_cast<const s16x8*>(ksb + 8192 + o0_);
      const s16x8 kb1 = *reinterpret_cast<const s16x8*>(ksb + 8192 + o1_);
      StA[nf] = mfma16(ka0, aq0, StA[nf]);
      StB[nf] = mfma16(kb0, aq0, StB[nf]);
      StA[nf] = mfma16(ka1, aq1, StA[nf]);
      StB[nf] = mfma16(kb1, aq1, StB[nf]);
    }

    const bool diagA = (s0 <= tbw + 19) && (s0 + 63 >= tbw - 4);
    const bool diagB = (s1 <= tbw + 19) && (s1 + 63 >= tbw - 4);

    if (diagA) {
#pragma unroll
      for (int nf = 0; nf < 4; ++nf)
#pragma unroll
        for (int r = 0; r < 4; ++r) {
          const int sd = (s0 + 16 * nf + 4 * lg + r) - qg;
          if (sd >= -4 && sd <= 4) StA[nf][r] += rkk[16 * wid + lr][sd + 4];
        }
    }
    if (diagB) {
#pragma unroll
      for (int nf = 0; nf < 4; ++nf)
#pragma unroll
        for (int r = 0; r < 4; ++r) {
          const int sd = (s1 + 16 * nf + 4 * lg + r) - qg;
          if (sd >= -4 && sd <= 4) StB[nf][r] += rkk[16 * wid + lr][sd + 4];
        }
    }
    if (!tflag[stp]) {
#pragma unroll
      for (int nf = 0; nf < 4; ++nf)
#pragma unroll
        for (int r = 0; r < 4; ++r)
          if (gmask[b * T + s0 + 16 * nf + 4 * lg + r] == 0) StA[nf][r] = MASKED;
    }
    if (!tflag[stp + 1]) {
#pragma unroll
      for (int nf = 0; nf < 4; ++nf)
#pragma unroll
        for (int r = 0; r < 4; ++r)
          if (gmask[b * T + s1 + 16 * nf + 4 * lg + r] == 0) StB[nf][r] = MASKED;
    }

    // --- ONE softmax chain over the 128-col pair ---
    float rm;
    {
      float mv = fmaxf(fmaxf(StA[0][0], StA[0][1]), fmaxf(StA[0][2], StA[0][3]));
#pragma unroll
      for (int nf = 1; nf < 4; ++nf)
        mv = fmaxf(mv, fmaxf(fmaxf(StA[nf][0], StA[nf][1]),
                             fmaxf(StA[nf][2], StA[nf][3])));
#pragma unroll
      for (int nf = 0; nf < 4; ++nf)
        mv = fmaxf(mv, fmaxf(fmaxf(StB[nf][0], StB[nf][1]),
                             fmaxf(StB[nf][2], StB[nf][3])));
      rm = mv;
      rm = fmaxf(rm, __shfl_xor(rm, 16));
      rm = fmaxf(rm, __shfl_xor(rm, 32));
    }
    if (!__all(rm - m <= DEFER_THR)) {  // deferred rescale (T13)
      const float mn = fmaxf(m, rm);
      const float corr = exp2f(m - mn);
#pragma unroll
      for (int nf = 0; nf < 4; ++nf) {
        Oa[nf][0] *= corr; Oa[nf][1] *= corr;
        Oa[nf][2] *= corr; Oa[nf][3] *= corr;
      }
      lsum *= corr;
      m = mn;
    }
    float rs = 0.f;
#pragma unroll
    for (int nf = 0; nf < 4; ++nf)
#pragma unroll
      for (int r = 0; r < 4; ++r) {
        const float pA = exp2f(StA[nf][r] - m);
        const float pB = exp2f(StB[nf][r] - m);
        StA[nf][r] = pA;
        StB[nf][r] = pB;
        rs += pA + pB;
      }
    rs += __shfl_xor(rs, 16);
    rs += __shfl_xor(rs, 32);
    lsum += rs;

    // --- P-diag buffer for rel-v (wave-local, covers the whole pair) ---
    const bool diagP = diagA || diagB;
    if (diagP) {
      u32* pz = (u32*)Pd;
      pz[l] = 0; pz[l + 64] = 0;
      if (diagA) {
#pragma unroll
        for (int nf = 0; nf < 4; ++nf)
#pragma unroll
          for (int r = 0; r < 4; ++r) {
            const int sd = (s0 + 16 * nf + 4 * lg + r) - qg;
            if (sd >= -4 && sd <= 4) Pd[lr * 16 + sd + 4] = f2bf(StA[nf][r]);
          }
      }
      if (diagB) {
#pragma unroll
        for (int nf = 0; nf < 4; ++nf)
#pragma unroll
          for (int r = 0; r < 4; ++r) {
            const int sd = (s1 + 16 * nf + 4 * lg + r) - qg;
            if (sd >= -4 && sd <= 4) Pd[lr * 16 + sd + 4] = f2bf(StB[nf][r]);
          }
      }
    }

    // --- tile A: redistribute + PV ---
    const char* vsb = (const char*)&Vbuf[cur][0];
    {
      s16x8 pa0, pa1;
      redist(StA, pa0, pa1);
#pragma unroll
      for (int nf = 0; nf < 4; ++nf) {
        const int dd = 16 * nf + lr;
        const int swz = (dd & 7) << 4;
        const s16x8 bv0 = *reinterpret_cast<const s16x8*>(
            vsb + ((dd * 128 + 16 * lg) ^ swz));
        const s16x8 bv1 = *reinterpret_cast<const s16x8*>(
            vsb + ((dd * 128 + 16 * (lg + 4)) ^ swz));
        Oa[nf] = mfma16(bv0, pa0, Oa[nf]);
        Oa[nf] = mfma16(bv1, pa1, Oa[nf]);
      }
    }
    // --- tile B: redistribute + PV ---
    {
      s16x8 pa0, pa1;
      redist(StB, pa0, pa1);
#pragma unroll
      for (int nf = 0; nf < 4; ++nf) {
        const int dd = 16 * nf + lr;
        const int swz = (dd & 7) << 4;
        const s16x8 bv0 = *reinterpret_cast<const s16x8*>(
            vsb + 8192 + ((dd * 128 + 16 * lg) ^ swz));
        const s16x8 bv1 = *reinterpret_cast<const s16x8*>(
            vsb + 8192 + ((dd * 128 + 16 * (lg + 4)) ^ swz));
        Oa[nf] = mfma16(bv0, pa0, Oa[nf]);
        Oa[nf] = mfma16(bv1, pa1, Oa[nf]);
      }
    }

    // --- rel-v: O += mfma(ev^T, Pdiag) once per pair ---
    if (diagP) {
      const u16* pdsrc = (lg < 2) ? &Pd[lr * 16 + 8 * lg] : &zerobuf[0];
      const s16x8 pd = *reinterpret_cast<const s16x8*>(pdsrc);
#pragma unroll
      for (int nf = 0; nf < 4; ++nf) Oa[nf] = mfma16(evA[nf], pd, Oa[nf]);
    }

    __syncthreads();
    cur ^= 1;
  }

  // ---- write unnormalized partials + (m,l) ----
  u16* op = shalf ? op1 : op0;
#pragma unroll
  for (int nf = 0; nf < 4; ++nf) {
    u16x4 pk;
#pragma unroll
    for (int r = 0; r < 4; ++r) pk[r] = f2bf(Oa[nf][r]);
    *reinterpret_cast<u16x4*>(
        &op[(bh * T + qg) * 64 + 16 * nf + 4 * lg]) = pk;
  }
  if (lg == 0) {
    float2 v;
    v.x = m;
    v.y = lsum;
    mlb[(size_t)shalf * 32768 + bh * T + qg] = v;
  }
}

// ---------------------------------------------------------------------------
// Output projection WITH FUSED MERGE: B-staging reads the two unnormalized
// s-half partials + per-row (m,l), merges inline, writes merged bf16 to LDS.
// out[b][o][t] = sum_c Wo[o][c] att[b][h(c)][t][dd(c)] + bo
// ---------------------------------------------------------------------------
__global__ __launch_bounds__(256) void out_gemm(
    const u16* __restrict__ Wob, const float* __restrict__ bo,
    const u16* __restrict__ op0, const u16* __restrict__ op1,
    const float2* __restrict__ mlb, float* __restrict__ out) {
  __shared__ u16 Bs[2][128 * 32];
  __shared__ float sbias[64];
  const int tid = threadIdx.x;
  const int b = blockIdx.z;
  const int o0 = blockIdx.y * 64;
  const int t0 = blockIdx.x * 128;
  if (tid < 16)
    *reinterpret_cast<float4*>(&sbias[tid * 4]) =
        *reinterpret_cast<const float4*>(&bo[o0 + tid * 4]);

  const int l = tid & 63, wid = tid >> 6;
  const int wm = wid >> 1, wn = wid & 1;
  const int lr = l & 15, lg = l >> 4;

  const int slot = tid & 3, trow = tid >> 2;
  const u16* Arow0 = Wob + (size_t)(o0 + 32 * wm + lr) * C + 8 * lg;
  const u16* Arow1 = Arow0 + 16 * C;

  f32x4 acc[2][4] = {};

  auto stage = [&](int kk, int buf) {
    const int c0 = kk * 32;
    const int h = c0 >> 6, dd0 = c0 & 63;
    char* base = (char*)&Bs[buf][0];
#pragma unroll
    for (int rep = 0; rep < 2; ++rep) {
      const int t = rep * 64 + trow;
      const size_t rowg = (size_t)((b * 8 + h) * T) + t0 + t;
      const float2 ml0 = mlb[rowg];
      const float2 ml1 = mlb[32768 + rowg];
      const float mm = fmaxf(ml0.x, ml1.x);
      const float a0 = exp2f(ml0.x - mm), a1 = exp2f(ml1.x - mm);
      const float inv = 1.0f / (a0 * ml0.y + a1 * ml1.y);
      const u16x8 v0 =
          *reinterpret_cast<const u16x8*>(&op0[rowg * 64 + dd0 + 8 * slot]);
      const u16x8 v1 =
          *reinterpret_cast<const u16x8*>(&op1[rowg * 64 + dd0 + 8 * slot]);
      u16x8 mv;
#pragma unroll
      for (int j = 0; j < 8; ++j)
        mv[j] = f2bf((bf2f(v0[j]) * a0 + bf2f(v1[j]) * a1) * inv);
      *(u16x8*)(base + ((t * 64 + 16 * slot) ^ ((t & 3) << 4))) = mv;
    }
  };

  s16x8 a0 = *reinterpret_cast<const s16x8*>(Arow0);
  s16x8 a1 = *reinterpret_cast<const s16x8*>(Arow1);
  stage(0, 0);
  __syncthreads();

  for (int kk = 0; kk < 16; ++kk) {
    s16x8 an0, an1;
    if (kk < 15) {
      an0 = *reinterpret_cast<const s16x8*>(Arow0 + (kk + 1) * 32);
      an1 = *reinterpret_cast<const s16x8*>(Arow1 + (kk + 1) * 32);
      stage(kk + 1, (kk + 1) & 1);
    }
    const char* rb = (const char*)&Bs[kk & 1][0];
#pragma unroll
    for (int nf = 0; nf < 4; ++nf) {
      const int t = 64 * wn + 16 * nf + lr;
      const s16x8 bfrag = *reinterpret_cast<const s16x8*>(
          rb + ((t * 64 + 16 * lg) ^ ((t & 3) << 4)));
      acc[0][nf] = mfma16(a0, bfrag, acc[0][nf]);
      acc[1][nf] = mfma16(a1, bfrag, acc[1][nf]);
    }
    __syncthreads();
    if (kk < 15) { a0 = an0; a1 = an1; }
  }

#pragma unroll
  for (int m = 0; m < 2; ++m) {
    const int ol = 32 * wm + 16 * m + 4 * lg;
#pragma unroll
    for (int nf = 0; nf < 4; ++nf) {
      const int t = t0 + 64 * wn + 16 * nf + lr;
#pragma unroll
      for (int r = 0; r < 4; ++r)
        out[((size_t)(b * C) + o0 + ol + r) * T + t] =
            acc[m][nf][r] + sbias[ol + r];
    }
  }
}

}  // namespace

extern "C" void kernel_launch(void* const* d_in, const int* in_sizes, int n_in,
                              void* d_out, int out_size, void* d_ws,
                              size_t ws_size, hipStream_t stream) {
  const float* x    = (const float*)d_in[0];
  const int*   mask = (const int*)d_in[1];
  const float* Wq   = (const float*)d_in[2];
  const float* bq   = (const float*)d_in[3];
  const float* Wk   = (const float*)d_in[4];
  const float* bk   = (const float*)d_in[5];
  const float* Wv   = (const float*)d_in[6];
  const float* bv   = (const float*)d_in[7];
  const float* Wo   = (const float*)d_in[8];
  const float* bo   = (const float*)d_in[9];
  const float* ek   = (const float*)d_in[10];
  const float* ev   = (const float*)d_in[11];
  float* out = (float*)d_out;

  char* ws = (char*)d_ws;
  u16* xb   = (u16*)(ws);                    // 4 MB; dead after qkv -> op0
  u16* Wqb  = (u16*)(ws + 4194304);          // 512 KB each
  u16* Wkb  = (u16*)(ws + 4718592);
  u16* Wvb  = (u16*)(ws + 5242880);
  u16* Wob  = (u16*)(ws + 5767168);
  u16* qb   = (u16*)(ws + 6291456);          // 4 MB  [B][H][T][64] (scaled)
  u16* kswz = (u16*)(ws + 10485760);         // 4 MB  swizzled K tile images
  u16* vswz = (u16*)(ws + 14680064);         // 4 MB  swizzled V tile images
  u16* op0  = xb;                            // 4 MB  partial O, s-half 0
  u16* op1  = (u16*)(ws + 23068672);         // 4 MB  partial O, s-half 1
  float2* mlb = (float2*)(ws + 27262976);    // 512 KB [2][B*H*T] (m,l)

  convert_all<<<dim3(3072), dim3(256), 0, stream>>>(x, Wq, Wk, Wv, Wo, xb, Wqb,
                                                    Wkb, Wvb, Wob);
  qkv_gemm<<<dim3(8, 8, 12), dim3(256), 0, stream>>>(xb, Wqb, Wkb, Wvb, bq, bk,
                                                     bv, qb, kswz, vswz);
  attn_swapped<<<dim3(8, 8, 8), dim3(512), 0, stream>>>(
      qb, kswz, vswz, mask, ek, ev, op0, op1, mlb);
  out_gemm<<<dim3(8, 8, 4), dim3(256), 0, stream>>>(Wob, bo, op0, op1, mlb,
                                                    out);
}

// Round 14
// 79.909 us; speedup vs baseline: 1.2342x; 1.2342x over previous
//
#include <hip/hip_runtime.h>

typedef unsigned short u16;
typedef unsigned int u32;
using f32x4 = __attribute__((ext_vector_type(4))) float;
using s16x8 = __attribute__((ext_vector_type(8))) short;
using u16x4 = __attribute__((ext_vector_type(4))) unsigned short;
using u16x8 = __attribute__((ext_vector_type(8))) unsigned short;

#define GLOAD_LDS16(g, s)                                     \
  __builtin_amdgcn_global_load_lds(                           \
      (const __attribute__((address_space(1))) void*)(g),     \
      (__attribute__((address_space(3))) void*)(s), 16, 0, 0)

namespace {

constexpr int T = 1024;
constexpr int C = 512;
constexpr float QSCALE = 0.125f * 1.4426950408889634f;  // 1/8 * log2(e)
constexpr float MASKED = -14427.0f;                     // -10000 * log2(e)
constexpr float DEFER_THR = 11.0f;

__device__ inline u16 f2bf(float f) {
  u32 u = __builtin_bit_cast(u32, f);
  u32 r = (u + 0x7fffu + ((u >> 16) & 1u)) >> 16;
  return (u16)r;
}
__device__ inline float bf2f(u16 v) {
  return __builtin_bit_cast(float, (u32)v << 16);
}
__device__ inline f32x4 mfma16(s16x8 a, s16x8 b, f32x4 c) {
  return __builtin_amdgcn_mfma_f32_16x16x32_bf16(a, b, c, 0, 0, 0);
}
__device__ inline u32 cvtpk(float lo, float hi) {
  u32 r;
  asm("v_cvt_pk_bf16_f32 %0, %1, %2" : "=v"(r) : "v"(lo), "v"(hi));
  return r;
}

// ---------------------------------------------------------------------------
// fp32 -> bf16 conversion (separate kernel: streaming, prefetch-friendly)
// ---------------------------------------------------------------------------
__global__ __launch_bounds__(256) void convert_all(
    const float* __restrict__ x, const float* __restrict__ Wq,
    const float* __restrict__ Wk, const float* __restrict__ Wv,
    const float* __restrict__ Wo, u16* __restrict__ xb, u16* __restrict__ Wqb,
    u16* __restrict__ Wkb, u16* __restrict__ Wvb, u16* __restrict__ Wob) {
  const int tid = threadIdx.x;
  const int bid = blockIdx.x;
  const float* src;
  u16* dst;
  size_t off;
  if (bid < 2048) {
    src = x; dst = xb;
    off = ((size_t)bid * 256 + tid) * 4;
  } else {
    const int j = bid - 2048;
    const int w = j >> 8;
    src = w == 0 ? Wq : w == 1 ? Wk : w == 2 ? Wv : Wo;
    dst = w == 0 ? Wqb : w == 1 ? Wkb : w == 2 ? Wvb : Wob;
    off = (((size_t)(j & 255)) * 256 + tid) * 4;
  }
  const float4 v = *reinterpret_cast<const float4*>(src + off);
  u16x4 o;
  o[0] = f2bf(v.x); o[1] = f2bf(v.y); o[2] = f2bf(v.z); o[3] = f2bf(v.w);
  *reinterpret_cast<u16x4*>(dst + off) = o;
}

// ---------------------------------------------------------------------------
// Fused q/k/v projection GEMM (bf16 MFMA).  Y[o][t] = sum_c W[o][c] x[c][t].
// q: [b][h][t][dd] bf16, PRE-SCALED by QSCALE (log2-domain scores).
// k,v: PRE-SWIZZLED tile images for linear DMA into LDS.
// ---------------------------------------------------------------------------
__global__ __launch_bounds__(256) void qkv_gemm(
    const u16* __restrict__ xb, const u16* __restrict__ Wqb,
    const u16* __restrict__ Wkb, const u16* __restrict__ Wvb,
    const float* __restrict__ bq, const float* __restrict__ bk,
    const float* __restrict__ bv, u16* __restrict__ qb, u16* __restrict__ kswz,
    u16* __restrict__ vswz) {
  __shared__ u16 Bs[2][128 * 32];
  __shared__ float sbias[64];
  const int tid = threadIdx.x;
  const int z = blockIdx.z;
  const int b = z / 3, wsel = z - 3 * b;
  const u16* W = wsel == 0 ? Wqb : wsel == 1 ? Wkb : Wvb;
  const float* bias = wsel == 0 ? bq : wsel == 1 ? bk : bv;
  const int o0 = blockIdx.y * 64;
  const int t0 = blockIdx.x * 128;
  if (tid < 16)
    *reinterpret_cast<float4*>(&sbias[tid * 4]) =
        *reinterpret_cast<const float4*>(&bias[o0 + tid * 4]);

  const int l = tid & 63, wid = tid >> 6;
  const int wm = wid >> 1, wn = wid & 1;
  const int lr = l & 15, lg = l >> 4;

  const int cpair = tid & 15, tgrp = tid >> 4;
  const u16* xrow =
      xb + ((size_t)(b * C) + 2 * cpair) * T + t0 + 8 * tgrp;

  const u16* Arow0 = W + (size_t)(o0 + 32 * wm + lr) * C + 8 * lg;
  const u16* Arow1 = Arow0 + 16 * C;

  f32x4 acc[2][4] = {};

  auto stage = [&](int kk, int buf) {
    const u16* p = xrow + (size_t)kk * 32 * T;
    const u16x8 v0 = *reinterpret_cast<const u16x8*>(p);
    const u16x8 v1 = *reinterpret_cast<const u16x8*>(p + T);
    char* base = (char*)&Bs[buf][0];
#pragma unroll
    for (int j = 0; j < 8; ++j) {
      const int t = 8 * tgrp + j;
      const u32 w2 = (u32)v0[j] | ((u32)v1[j] << 16);
      *(u32*)(base + ((t * 64 + 4 * cpair) ^ ((t & 3) << 4))) = w2;
    }
  };

  s16x8 a0 = *reinterpret_cast<const s16x8*>(Arow0);
  s16x8 a1 = *reinterpret_cast<const s16x8*>(Arow1);
  stage(0, 0);
  __syncthreads();

  for (int kk = 0; kk < 16; ++kk) {
    s16x8 an0, an1;
    if (kk < 15) {
      an0 = *reinterpret_cast<const s16x8*>(Arow0 + (kk + 1) * 32);
      an1 = *reinterpret_cast<const s16x8*>(Arow1 + (kk + 1) * 32);
      stage(kk + 1, (kk + 1) & 1);
    }
    const char* rb = (const char*)&Bs[kk & 1][0];
#pragma unroll
    for (int nf = 0; nf < 4; ++nf) {
      const int t = 64 * wn + 16 * nf + lr;
      const s16x8 bfrag = *reinterpret_cast<const s16x8*>(
          rb + ((t * 64 + 16 * lg) ^ ((t & 3) << 4)));
      acc[0][nf] = mfma16(a0, bfrag, acc[0][nf]);
      acc[1][nf] = mfma16(a1, bfrag, acc[1][nf]);
    }
    __syncthreads();
    if (kk < 15) { a0 = an0; a1 = an1; }
  }

  const int h = o0 >> 6;
  const size_t bh = (size_t)(b * 8 + h);
  if (wsel == 0) {
#pragma unroll
    for (int m = 0; m < 2; ++m) {
      const int ob = 32 * wm + 16 * m + 4 * lg;
#pragma unroll
      for (int nf = 0; nf < 4; ++nf) {
        const int t = t0 + 64 * wn + 16 * nf + lr;
        u16x4 pk;
#pragma unroll
        for (int r = 0; r < 4; ++r)
          pk[r] = f2bf((acc[m][nf][r] + sbias[ob + r]) * QSCALE);
        *reinterpret_cast<u16x4*>(&qb[(bh * T + t) * 64 + ob]) = pk;
      }
    }
  } else if (wsel == 1) {  // K -> swizzled tile image
    char* kbase = (char*)kswz;
#pragma unroll
    for (int m = 0; m < 2; ++m) {
      const int ob = 32 * wm + 16 * m + 4 * lg;
#pragma unroll
      for (int nf = 0; nf < 4; ++nf) {
        const int t = t0 + 64 * wn + 16 * nf + lr;
        const int tile = t >> 6, row = t & 63;
        u16x4 pk;
#pragma unroll
        for (int r = 0; r < 4; ++r) pk[r] = f2bf(acc[m][nf][r] + sbias[ob + r]);
        const int off = (row * 128 + 2 * ob) ^ ((row & 7) << 4);
        *(u16x4*)(kbase + (bh * 16 + tile) * 8192 + off) = pk;
      }
    }
  } else {  // V -> swizzled tile image, scalar stores
    char* vbase = (char*)vswz;
#pragma unroll
    for (int m = 0; m < 2; ++m) {
      const int ob = 32 * wm + 16 * m + 4 * lg;
#pragma unroll
      for (int nf = 0; nf < 4; ++nf) {
        const int t = t0 + 64 * wn + 16 * nf + lr;
        const int tile = t >> 6, col2 = 2 * (t & 63);
#pragma unroll
        for (int r = 0; r < 4; ++r) {
          const int dd = ob + r;
          const int off = (dd * 128 + col2) ^ ((dd & 7) << 4);
          *(u16*)(vbase + (bh * 16 + tile) * 8192 + off) =
              f2bf(acc[m][nf][r] + sbias[dd]);
        }
      }
    }
  }
}

// ---------------------------------------------------------------------------
// MFMA flash attention (R10-proven) + XCD-AWARE BLOCK REMAP:
// dispatch-linear p%8 ~ XCD; remap so XCD k owns all h-groups of one
// (b,shalf) -> each XCD's L2 caches only its own 2 MB of Q/K/V images.
// swapped QK^T, in-register softmax, 8-wave blocks, split-2, pair processing.
// ---------------------------------------------------------------------------
__global__ __launch_bounds__(512) void attn_swapped(
    const u16* __restrict__ qb, const u16* __restrict__ kswz,
    const u16* __restrict__ vswz, const int* __restrict__ gmask,
    const float* __restrict__ ek, const float* __restrict__ ev,
    u16* __restrict__ op0, u16* __restrict__ op1, float2* __restrict__ mlb) {
  __shared__ u16 Kbuf[2][8192];   // pair image: 2 tiles x 4096 u16 (16 KB)
  __shared__ u16 Vbuf[2][8192];
  __shared__ u16 Pdiag[8][256];
  __shared__ float rkk[128][12];
  __shared__ float eks[9][64];
  __shared__ float evs[9][64];
  __shared__ u16 zerobuf[16];
  __shared__ int tflag[16];

  // ---- XCD-aware remap (bijective on the 512-block grid) ----
  const int p = blockIdx.x + 8 * blockIdx.y + 64 * blockIdx.z;
  const int xcd = p & 7;              // dispatch round-robin -> XCD
  const int slot = p >> 3;            // 0..63 within this XCD
  const int zz = xcd;                 // (b,shalf) group pinned to this XCD
  const int h = slot >> 3;            // 8 heads per XCD
  const int tcx = slot & 7;           // t-chunk
  const int b = zz >> 1, shalf = zz & 1;
  const int tc = tcx * 128;

  const int tid = threadIdx.x;
  const int l = tid & 63, wid = tid >> 6;  // 8 waves
  const int lr = l & 15, lg = l >> 4;

  const size_t bh = (size_t)(b * 8 + h);
  const u16* qbh = qb + bh * T * 64;
  const u16* kimg0 = kswz + bh * 65536;
  const u16* vimg0 = vswz + bh * 65536;

  if (tid < 144) {
    reinterpret_cast<float4*>(&eks[0][0])[tid] =
        reinterpret_cast<const float4*>(ek)[tid];
    reinterpret_cast<float4*>(&evs[0][0])[tid] =
        reinterpret_cast<const float4*>(ev)[tid];
  }
  if (tid < 16) { tflag[tid] = 1; zerobuf[tid] = 0; }
  __syncthreads();  // eks/evs visible

  // async stage of a PAIR of K/V tiles (16 KB each of K and V)
  auto stage_pair = [&](int stp, int buf) {
    const u16* ki = kimg0 + (size_t)stp * 4096;
    const u16* vi = vimg0 + (size_t)stp * 4096;
#pragma unroll
    for (int j = 0; j < 2; ++j) {
      const int seg = wid + 8 * j;  // 16 segments x 512 u16
      GLOAD_LDS16(ki + seg * 512 + l * 8, &Kbuf[buf][seg * 512]);
      GLOAD_LDS16(vi + seg * 512 + l * 8, &Vbuf[buf][seg * 512]);
    }
  };
  const int st0 = shalf * 8;
  stage_pair(st0, 0);  // flies under the prologue below

  // per-tile mask flags (all-ones fast path)
  if (tid < 256) {
    const int4 mm = reinterpret_cast<const int4*>(gmask + b * T)[tid];
    if (!(mm.x && mm.y && mm.z && mm.w)) tflag[tid >> 4] = 0;  // benign race
  }

  {  // rkk[r][w] = Qscaled[tc+r].ek[w]: 4 threads per row, 2-shuffle reduce
    const int r = tid >> 2, sub = tid & 3;
    const u16* qp = qbh + (size_t)(tc + r) * 64 + sub * 16;
    const u16x8 q0 = *reinterpret_cast<const u16x8*>(qp);
    const u16x8 q1 = *reinterpret_cast<const u16x8*>(qp + 8);
    float qf[16];
#pragma unroll
    for (int j = 0; j < 8; ++j) {
      qf[j] = bf2f(q0[j]);
      qf[j + 8] = bf2f(q1[j]);
    }
    float part[9];
#pragma unroll
    for (int w = 0; w < 9; ++w) {
      float s = 0.f;
      const float* er = &eks[w][sub * 16];
#pragma unroll
      for (int d = 0; d < 16; ++d) s += qf[d] * er[d];
      part[w] = s;
    }
#pragma unroll
    for (int w = 0; w < 9; ++w) {
      part[w] += __shfl_xor(part[w], 1);
      part[w] += __shfl_xor(part[w], 2);
    }
    if (sub == 0) {
#pragma unroll
      for (int w = 0; w < 9; ++w) rkk[r][w] = part[w];
    }
  }

  // Q B-frags direct from global (L2-hot)
  const int tbw = tc + 16 * wid;
  const int qg = tbw + lr;
  s16x8 aq0, aq1;
  {
    const u16* qgp = qbh + (size_t)qg * 64;
    aq0 = *reinterpret_cast<const s16x8*>(qgp + 8 * lg);
    aq1 = *reinterpret_cast<const s16x8*>(qgp + 32 + 8 * lg);
  }

  // ev^T A-fragments (rows dd, k = w zero-padded)
  s16x8 evA[4];
#pragma unroll
  for (int nf = 0; nf < 4; ++nf) {
    const int dd = 16 * nf + lr;
#pragma unroll
    for (int e = 0; e < 8; ++e) {
      float v = 0.f;
      if (lg == 0) v = evs[e][dd];
      else if (lg == 1 && e == 0) v = evs[8][dd];
      evA[nf][e] = (short)f2bf(v);
    }
  }

  float m = -1e30f, lsum = 0.f;
  f32x4 Oa[4] = {};
  u16* Pd = &Pdiag[wid][0];

  __syncthreads();  // rkk + tflag visible; pair-0 DMA drained

  // pack fp32 P-quad + redistribute into the PV B-fragment lane layout
  auto redist = [&](const f32x4* St, s16x8& pv0, s16x8& pv1) {
    u32 wpk[4][2];
#pragma unroll
    for (int nf = 0; nf < 4; ++nf) {
      wpk[nf][0] = cvtpk(St[nf][0], St[nf][1]);
      wpk[nf][1] = cvtpk(St[nf][2], St[nf][3]);
    }
    const int srcLo = lr + ((lg & 1) << 5);
    const int srcHi = srcLo + 16;
    const bool hiSel = (lg >> 1) != 0;
    union { u32 u[4]; s16x8 v; } pa0, pa1;
    {
      const u32 a0_ = __shfl((int)wpk[0][0], srcLo), b0_ = __shfl((int)wpk[1][0], srcLo);
      const u32 a1_ = __shfl((int)wpk[0][1], srcLo), b1_ = __shfl((int)wpk[1][1], srcLo);
      const u32 a2_ = __shfl((int)wpk[0][0], srcHi), b2_ = __shfl((int)wpk[1][0], srcHi);
      const u32 a3_ = __shfl((int)wpk[0][1], srcHi), b3_ = __shfl((int)wpk[1][1], srcHi);
      pa0.u[0] = hiSel ? b0_ : a0_; pa0.u[1] = hiSel ? b1_ : a1_;
      pa0.u[2] = hiSel ? b2_ : a2_; pa0.u[3] = hiSel ? b3_ : a3_;
    }
    {
      const u32 a0_ = __shfl((int)wpk[2][0], srcLo), b0_ = __shfl((int)wpk[3][0], srcLo);
      const u32 a1_ = __shfl((int)wpk[2][1], srcLo), b1_ = __shfl((int)wpk[3][1], srcLo);
      const u32 a2_ = __shfl((int)wpk[2][0], srcHi), b2_ = __shfl((int)wpk[3][0], srcHi);
      const u32 a3_ = __shfl((int)wpk[2][1], srcHi), b3_ = __shfl((int)wpk[3][1], srcHi);
      pa1.u[0] = hiSel ? b0_ : a0_; pa1.u[1] = hiSel ? b1_ : a1_;
      pa1.u[2] = hiSel ? b2_ : a2_; pa1.u[3] = hiSel ? b3_ : a3_;
    }
    pv0 = pa0.v;
    pv1 = pa1.v;
  };

  int cur = 0;
  for (int ii = 0; ii < 4; ++ii) {
    const int stp = st0 + 2 * ii;
    const int s0 = stp * 64, s1 = s0 + 64;
    if (ii < 3) stage_pair(stp + 2, cur ^ 1);

    // S^T = K Q^T for BOTH tiles (two independent chains)
    f32x4 StA[4] = {}, StB[4] = {};
    const char* ksb = (const char*)&Kbuf[cur][0];
#pragma unroll
    for (int nf = 0; nf < 4; ++nf) {
      const int srow = 16 * nf + lr;
      const int swz = (srow & 7) << 4;
      const int o0_ = (srow * 128 + 16 * lg) ^ swz;
      const int o1_ = (srow * 128 + 16 * (lg + 4)) ^ swz;
      const s16x8 ka0 = *reinterpret_cast<const s16x8*>(ksb + o0_);
      const s16x8 ka1 = *reinterpret_cast<const s16x8*>(ksb + o1_);
      const s16x8 kb0 = *reinterpret_cast<const s16x8*>(ksb + 8192 + o0_);
      const s16x8 kb1 = *reinterpret_cast<const s16x8*>(ksb + 8192 + o1_);
      StA[nf] = mfma16(ka0, aq0, StA[nf]);
      StB[nf] = mfma16(kb0, aq0, StB[nf]);
      StA[nf] = mfma16(ka1, aq1, StA[nf]);
      StB[nf] = mfma16(kb1, aq1, StB[nf]);
    }

    const bool diagA = (s0 <= tbw + 19) && (s0 + 63 >= tbw - 4);
    const bool diagB = (s1 <= tbw + 19) && (s1 + 63 >= tbw - 4);

    if (diagA) {
#pragma unroll
      for (int nf = 0; nf < 4; ++nf)
#pragma unroll
        for (int r = 0; r < 4; ++r) {
          const int sd = (s0 + 16 * nf + 4 * lg + r) - qg;
          if (sd >= -4 && sd <= 4) StA[nf][r] += rkk[16 * wid + lr][sd + 4];
        }
    }
    if (diagB) {
#pragma unroll
      for (int nf = 0; nf < 4; ++nf)
#pragma unroll
        for (int r = 0; r < 4; ++r) {
          const int sd = (s1 + 16 * nf + 4 * lg + r) - qg;
          if (sd >= -4 && sd <= 4) StB[nf][r] += rkk[16 * wid + lr][sd + 4];
        }
    }
    if (!tflag[stp]) {
#pragma unroll
      for (int nf = 0; nf < 4; ++nf)
#pragma unroll
        for (int r = 0; r < 4; ++r)
          if (gmask[b * T + s0 + 16 * nf + 4 * lg + r] == 0) StA[nf][r] = MASKED;
    }
    if (!tflag[stp + 1]) {
#pragma unroll
      for (int nf = 0; nf < 4; ++nf)
#pragma unroll
        for (int r = 0; r < 4; ++r)
          if (gmask[b * T + s1 + 16 * nf + 4 * lg + r] == 0) StB[nf][r] = MASKED;
    }

    // --- ONE softmax chain over the 128-col pair ---
    float rm;
    {
      float mv = fmaxf(fmaxf(StA[0][0], StA[0][1]), fmaxf(StA[0][2], StA[0][3]));
#pragma unroll
      for (int nf = 1; nf < 4; ++nf)
        mv = fmaxf(mv, fmaxf(fmaxf(StA[nf][0], StA[nf][1]),
                             fmaxf(StA[nf][2], StA[nf][3])));
#pragma unroll
      for (int nf = 0; nf < 4; ++nf)
        mv = fmaxf(mv, fmaxf(fmaxf(StB[nf][0], StB[nf][1]),
                             fmaxf(StB[nf][2], StB[nf][3])));
      rm = mv;
      rm = fmaxf(rm, __shfl_xor(rm, 16));
      rm = fmaxf(rm, __shfl_xor(rm, 32));
    }
    if (!__all(rm - m <= DEFER_THR)) {  // deferred rescale (T13)
      const float mn = fmaxf(m, rm);
      const float corr = exp2f(m - mn);
#pragma unroll
      for (int nf = 0; nf < 4; ++nf) {
        Oa[nf][0] *= corr; Oa[nf][1] *= corr;
        Oa[nf][2] *= corr; Oa[nf][3] *= corr;
      }
      lsum *= corr;
      m = mn;
    }
    float rs = 0.f;
#pragma unroll
    for (int nf = 0; nf < 4; ++nf)
#pragma unroll
      for (int r = 0; r < 4; ++r) {
        const float pA = exp2f(StA[nf][r] - m);
        const float pB = exp2f(StB[nf][r] - m);
        StA[nf][r] = pA;
        StB[nf][r] = pB;
        rs += pA + pB;
      }
    rs += __shfl_xor(rs, 16);
    rs += __shfl_xor(rs, 32);
    lsum += rs;

    // --- P-diag buffer for rel-v (wave-local, covers the whole pair) ---
    const bool diagP = diagA || diagB;
    if (diagP) {
      u32* pz = (u32*)Pd;
      pz[l] = 0; pz[l + 64] = 0;
      if (diagA) {
#pragma unroll
        for (int nf = 0; nf < 4; ++nf)
#pragma unroll
          for (int r = 0; r < 4; ++r) {
            const int sd = (s0 + 16 * nf + 4 * lg + r) - qg;
            if (sd >= -4 && sd <= 4) Pd[lr * 16 + sd + 4] = f2bf(StA[nf][r]);
          }
      }
      if (diagB) {
#pragma unroll
        for (int nf = 0; nf < 4; ++nf)
#pragma unroll
          for (int r = 0; r < 4; ++r) {
            const int sd = (s1 + 16 * nf + 4 * lg + r) - qg;
            if (sd >= -4 && sd <= 4) Pd[lr * 16 + sd + 4] = f2bf(StB[nf][r]);
          }
      }
    }

    // --- tile A: redistribute + PV ---
    const char* vsb = (const char*)&Vbuf[cur][0];
    {
      s16x8 pa0, pa1;
      redist(StA, pa0, pa1);
#pragma unroll
      for (int nf = 0; nf < 4; ++nf) {
        const int dd = 16 * nf + lr;
        const int swz = (dd & 7) << 4;
        const s16x8 bv0 = *reinterpret_cast<const s16x8*>(
            vsb + ((dd * 128 + 16 * lg) ^ swz));
        const s16x8 bv1 = *reinterpret_cast<const s16x8*>(
            vsb + ((dd * 128 + 16 * (lg + 4)) ^ swz));
        Oa[nf] = mfma16(bv0, pa0, Oa[nf]);
        Oa[nf] = mfma16(bv1, pa1, Oa[nf]);
      }
    }
    // --- tile B: redistribute + PV ---
    {
      s16x8 pa0, pa1;
      redist(StB, pa0, pa1);
#pragma unroll
      for (int nf = 0; nf < 4; ++nf) {
        const int dd = 16 * nf + lr;
        const int swz = (dd & 7) << 4;
        const s16x8 bv0 = *reinterpret_cast<const s16x8*>(
            vsb + 8192 + ((dd * 128 + 16 * lg) ^ swz));
        const s16x8 bv1 = *reinterpret_cast<const s16x8*>(
            vsb + 8192 + ((dd * 128 + 16 * (lg + 4)) ^ swz));
        Oa[nf] = mfma16(bv0, pa0, Oa[nf]);
        Oa[nf] = mfma16(bv1, pa1, Oa[nf]);
      }
    }

    // --- rel-v: O += mfma(ev^T, Pdiag) once per pair ---
    if (diagP) {
      const u16* pdsrc = (lg < 2) ? &Pd[lr * 16 + 8 * lg] : &zerobuf[0];
      const s16x8 pd = *reinterpret_cast<const s16x8*>(pdsrc);
#pragma unroll
      for (int nf = 0; nf < 4; ++nf) Oa[nf] = mfma16(evA[nf], pd, Oa[nf]);
    }

    __syncthreads();
    cur ^= 1;
  }

  // ---- write unnormalized partials + (m,l) ----
  u16* op = shalf ? op1 : op0;
#pragma unroll
  for (int nf = 0; nf < 4; ++nf) {
    u16x4 pk;
#pragma unroll
    for (int r = 0; r < 4; ++r) pk[r] = f2bf(Oa[nf][r]);
    *reinterpret_cast<u16x4*>(
        &op[(bh * T + qg) * 64 + 16 * nf + 4 * lg]) = pk;
  }
  if (lg == 0) {
    float2 v;
    v.x = m;
    v.y = lsum;
    mlb[(size_t)shalf * 32768 + bh * T + qg] = v;
  }
}

// ---------------------------------------------------------------------------
// Merge the two s-half partials (m in log2 domain -> exp2).
// ---------------------------------------------------------------------------
__global__ __launch_bounds__(256) void merge_halves(
    const u16* __restrict__ op0, const u16* __restrict__ op1,
    const float2* __restrict__ mlb, u16* __restrict__ attb) {
  const int tid = threadIdx.x;
  const int row = blockIdx.x * 16 + (tid >> 4);
  const int dd = (tid & 15) * 4;
  const float2 ml0 = mlb[row];
  const float2 ml1 = mlb[32768 + row];
  const float mm = fmaxf(ml0.x, ml1.x);
  const float a0 = exp2f(ml0.x - mm), a1 = exp2f(ml1.x - mm);
  const float inv = 1.0f / (a0 * ml0.y + a1 * ml1.y);
  const u16x4 v0 = *reinterpret_cast<const u16x4*>(&op0[(size_t)row * 64 + dd]);
  const u16x4 v1 = *reinterpret_cast<const u16x4*>(&op1[(size_t)row * 64 + dd]);
  u16x4 o;
#pragma unroll
  for (int j = 0; j < 4; ++j)
    o[j] = f2bf((bf2f(v0[j]) * a0 + bf2f(v1[j]) * a1) * inv);
  *reinterpret_cast<u16x4*>(&attb[(size_t)row * 64 + dd]) = o;
}

// ---------------------------------------------------------------------------
// Output projection: out[b][o][t] = sum_c Wo[o][c] att[b][h(c)][t][dd(c)] + bo
// ---------------------------------------------------------------------------
__global__ __launch_bounds__(256) void out_gemm(
    const u16* __restrict__ Wob, const float* __restrict__ bo,
    const u16* __restrict__ attb, float* __restrict__ out) {
  __shared__ u16 Bs[2][128 * 32];
  __shared__ float sbias[64];
  const int tid = threadIdx.x;
  const int b = blockIdx.z;
  const int o0 = blockIdx.y * 64;
  const int t0 = blockIdx.x * 128;
  if (tid < 16)
    *reinterpret_cast<float4*>(&sbias[tid * 4]) =
        *reinterpret_cast<const float4*>(&bo[o0 + tid * 4]);

  const int l = tid & 63, wid = tid >> 6;
  const int wm = wid >> 1, wn = wid & 1;
  const int lr = l & 15, lg = l >> 4;

  const int slot = tid & 3, trow = tid >> 2;
  const u16* Arow0 = Wob + (size_t)(o0 + 32 * wm + lr) * C + 8 * lg;
  const u16* Arow1 = Arow0 + 16 * C;

  f32x4 acc[2][4] = {};

  auto stage = [&](int kk, int buf) {
    const int c0 = kk * 32;
    const int h = c0 >> 6, dd0 = c0 & 63;
    char* base = (char*)&Bs[buf][0];
#pragma unroll
    for (int rep = 0; rep < 2; ++rep) {
      const int t = rep * 64 + trow;
      const u16x8 v = *reinterpret_cast<const u16x8*>(
          &attb[((size_t)((b * 8 + h) * T) + t0 + t) * 64 + dd0 + 8 * slot]);
      *(u16x8*)(base + ((t * 64 + 16 * slot) ^ ((t & 3) << 4))) = v;
    }
  };

  s16x8 a0 = *reinterpret_cast<const s16x8*>(Arow0);
  s16x8 a1 = *reinterpret_cast<const s16x8*>(Arow1);
  stage(0, 0);
  __syncthreads();

  for (int kk = 0; kk < 16; ++kk) {
    s16x8 an0, an1;
    if (kk < 15) {
      an0 = *reinterpret_cast<const s16x8*>(Arow0 + (kk + 1) * 32);
      an1 = *reinterpret_cast<const s16x8*>(Arow1 + (kk + 1) * 32);
      stage(kk + 1, (kk + 1) & 1);
    }
    const char* rb = (const char*)&Bs[kk & 1][0];
#pragma unroll
    for (int nf = 0; nf < 4; ++nf) {
      const int t = 64 * wn + 16 * nf + lr;
      const s16x8 bfrag = *reinterpret_cast<const s16x8*>(
          rb + ((t * 64 + 16 * lg) ^ ((t & 3) << 4)));
      acc[0][nf] = mfma16(a0, bfrag, acc[0][nf]);
      acc[1][nf] = mfma16(a1, bfrag, acc[1][nf]);
    }
    __syncthreads();
    if (kk < 15) { a0 = an0; a1 = an1; }
  }

#pragma unroll
  for (int m = 0; m < 2; ++m) {
    const int ol = 32 * wm + 16 * m + 4 * lg;
#pragma unroll
    for (int nf = 0; nf < 4; ++nf) {
      const int t = t0 + 64 * wn + 16 * nf + lr;
#pragma unroll
      for (int r = 0; r < 4; ++r)
        out[((size_t)(b * C) + o0 + ol + r) * T + t] =
            acc[m][nf][r] + sbias[ol + r];
    }
  }
}

}  // namespace

extern "C" void kernel_launch(void* const* d_in, const int* in_sizes, int n_in,
                              void* d_out, int out_size, void* d_ws,
                              size_t ws_size, hipStream_t stream) {
  const float* x    = (const float*)d_in[0];
  const int*   mask = (const int*)d_in[1];
  const float* Wq   = (const float*)d_in[2];
  const float* bq   = (const float*)d_in[3];
  const float* Wk   = (const float*)d_in[4];
  const float* bk   = (const float*)d_in[5];
  const float* Wv   = (const float*)d_in[6];
  const float* bv   = (const float*)d_in[7];
  const float* Wo   = (const float*)d_in[8];
  const float* bo   = (const float*)d_in[9];
  const float* ek   = (const float*)d_in[10];
  const float* ev   = (const float*)d_in[11];
  float* out = (float*)d_out;

  char* ws = (char*)d_ws;
  u16* xb   = (u16*)(ws);                    // 4 MB; dead after qkv -> op0
  u16* Wqb  = (u16*)(ws + 4194304);          // 512 KB each
  u16* Wkb  = (u16*)(ws + 4718592);
  u16* Wvb  = (u16*)(ws + 5242880);
  u16* Wob  = (u16*)(ws + 5767168);
  u16* qb   = (u16*)(ws + 6291456);          // 4 MB  [B][H][T][64] (scaled)
  u16* kswz = (u16*)(ws + 10485760);         // 4 MB  swizzled K tile images
  u16* vswz = (u16*)(ws + 14680064);         // 4 MB  swizzled V tile images
  u16* attb = (u16*)(ws + 18874368);         // 4 MB  [B][H][T][64]
  u16* op0  = xb;                            // 4 MB  partial O, s-half 0
  u16* op1  = (u16*)(ws + 23068672);         // 4 MB  partial O, s-half 1
  float2* mlb = (float2*)(ws + 27262976);    // 512 KB [2][B*H*T] (m,l)

  convert_all<<<dim3(3072), dim3(256), 0, stream>>>(x, Wq, Wk, Wv, Wo, xb, Wqb,
                                                    Wkb, Wvb, Wob);
  qkv_gemm<<<dim3(8, 8, 12), dim3(256), 0, stream>>>(xb, Wqb, Wkb, Wvb, bq, bk,
                                                     bv, qb, kswz, vswz);
  attn_swapped<<<dim3(8, 8, 8), dim3(512), 0, stream>>>(
      qb, kswz, vswz, mask, ek, ev, op0, op1, mlb);
  merge_halves<<<dim3(2048), dim3(256), 0, stream>>>(op0, op1, mlb, attb);
  out_gemm<<<dim3(8, 8, 4), dim3(256), 0, stream>>>(Wob, bo, attb, out);
}